// Round 11
// baseline (163.545 us; speedup 1.0000x reference)
//
#include <hip/hip_runtime.h>
#include <hip/hip_bf16.h>

#define N_FEAT 128     // D_FEAT == UNITS == 128
#define EPT 4          // edges per thread in partition passes
#define CHUNK 1024     // 256 threads * EPT  (R11: was 2048; 782 blocks ~ 3/CU)
#define BSHIFT 8       // bucket = node >> 8
#define MAXRANGE 256
#define CAP 8192       // per-bucket slot capacity (padded sum ~4900 expected; huge margin)
#define LSTR 66        // LDS row stride in dwords for the pooled tile

typedef short bf16x8 __attribute__((ext_vector_type(8)));
typedef float f32x4  __attribute__((ext_vector_type(4)));

__device__ __forceinline__ unsigned short f2bf_rtne(float f) {
    unsigned u = __float_as_uint(f);
    u += 0x7fffu + ((u >> 16) & 1u);
    return (unsigned short)(u >> 16);
}
__device__ __forceinline__ float bf2f(unsigned short h) {
    return __uint_as_float((unsigned)h << 16);
}
__device__ __forceinline__ int wave_incl_scan(int v, int lane) {
    #pragma unroll
    for (int d = 1; d < 64; d <<= 1) {
        int t = __shfl_up(v, d);
        if (lane >= d) v += t;
    }
    return v;
}

// ---------------------------------------------------------------------------
// K1: scatter into fixed-capacity buckets. R11: per-wave sub-histograms and
// per-wave cursors (no cross-wave LDS-atomic same-address contention),
// shfl-based block scan (5 barriers total, was ~20), CHUNK=1024.
// ---------------------------------------------------------------------------
__global__ __launch_bounds__(256) void scatter_kernel(const int* __restrict__ source,
                                                      const int* __restrict__ target,
                                                      int* __restrict__ curT,
                                                      int* __restrict__ curS,
                                                      unsigned int* __restrict__ pairsT,
                                                      unsigned char* __restrict__ srcB,
                                                      int E, int NB) {
    __shared__ int ht[4][MAXRANGE];                // per-wave target-bucket hist
    __shared__ int hs[4][MAXRANGE];                // per-wave source-bucket hist
    __shared__ unsigned int   lds_pairs[CHUNK];    // 4 KB
    __shared__ unsigned short lds_sp[CHUNK];       // 2 KB
    __shared__ int st[MAXRANGE], ss[MAXRANGE];     // block-exclusive starts
    __shared__ int gt[MAXRANGE], gs[MAXRANGE];     // reserved global run bases
    __shared__ int cwT[4][MAXRANGE], cwS[4][MAXRANGE];  // per-wave cursors
    __shared__ int wsumT[4], wsumS[4];
    int tid = threadIdx.x, lane = tid & 63, w = tid >> 6, b = blockIdx.x;
    int base = b * CHUNK;
    int cnt = E - base; if (cnt > CHUNK) cnt = CHUNK;

    #pragma unroll
    for (int i = 0; i < 4; ++i) { ht[i][tid] = 0; hs[i][tid] = 0; }
    __syncthreads();
    int rs[EPT], rt[EPT];
    #pragma unroll
    for (int j = 0; j < EPT; ++j) {
        int e = base + j * 256 + tid;
        if (e < E) {
            int s = source[e], t = target[e];
            rs[j] = s; rt[j] = t;
            atomicAdd(&ht[w][t >> BSHIFT], 1);
            atomicAdd(&hs[w][s >> BSHIFT], 1);
        }
    }
    __syncthreads();
    int k = tid;
    int h0 = ht[0][k], h1 = ht[1][k], h2 = ht[2][k], h3 = ht[3][k];
    int hT = h0 + h1 + h2 + h3;
    int q0 = hs[0][k], q1 = hs[1][k], q2 = hs[2][k], q3 = hs[3][k];
    int hS = q0 + q1 + q2 + q3;
    int iT = wave_incl_scan(hT, lane);
    int iS = wave_incl_scan(hS, lane);
    if (lane == 63) { wsumT[w] = iT; wsumS[w] = iS; }
    __syncthreads();
    int bT = 0, bS = 0;
    #pragma unroll
    for (int i = 0; i < 4; ++i) if (i < w) { bT += wsumT[i]; bS += wsumS[i]; }
    int exclT = bT + iT - hT;
    int exclS = bS + iS - hS;
    int gT = 0, gS = 0;
    if (k < NB) {
        if (hT) gT = atomicAdd(&curT[k], hT);
        if (hS) gS = atomicAdd(&curS[k], hS);
    }
    st[k] = exclT; ss[k] = exclS;
    gt[k] = gT;    gs[k] = gS;
    cwT[0][k] = exclT;                cwS[0][k] = exclS;
    cwT[1][k] = exclT + h0;           cwS[1][k] = exclS + q0;
    cwT[2][k] = exclT + h0 + h1;      cwS[2][k] = exclS + q0 + q1;
    cwT[3][k] = exclT + h0 + h1 + h2; cwS[3][k] = exclS + q0 + q1 + q2;
    __syncthreads();
    #pragma unroll
    for (int j = 0; j < EPT; ++j) {
        int e = base + j * 256 + tid;
        if (e < E) {
            int s = rs[j], t = rt[j];
            int kk = t >> BSHIFT;
            int p = atomicAdd(&cwT[w][kk], 1);        // intra-wave contention only
            lds_pairs[p] = (unsigned)s | ((unsigned)t << 16);
            int k2 = s >> BSHIFT;
            int p2 = atomicAdd(&cwS[w][k2], 1);
            lds_sp[p2] = (unsigned short)s;
        }
    }
    __syncthreads();
    for (int i = tid; i < cnt; i += 256) {
        unsigned ww = lds_pairs[i];
        int kk = ww >> 24;
        pairsT[(size_t)kk * CAP + gt[kk] + (i - st[kk])] = ww;
        unsigned short sp = lds_sp[i];
        int k2 = sp >> 8;
        srcB[(size_t)k2 * CAP + gs[k2] + (i - ss[k2])] = (unsigned char)sp;
    }
}

// ---------------------------------------------------------------------------
// K2: fused prep — grid of 2*NB+9 blocks:
//   b in [0,NB):        so+prescale for source bucket b (sub-hist, u32 reads)
//   b in [NB,2NB):      CSR build, degrees PADDED to multiple of 4 with dummy
//                       index N (zero row) so agg runs uniform aligned batches
//   b in [2NB,2NB+8):   W pack into MFMA B-fragment order (hi/lo split)
//   b == 2NB+8:         zero the dummy xb row N
// ---------------------------------------------------------------------------
__global__ __launch_bounds__(256) void prep_kernel(const unsigned char* __restrict__ srcB,
                                                   const unsigned int* __restrict__ pairsT,
                                                   const int* __restrict__ curT,
                                                   const int* __restrict__ curS,
                                                   const float* __restrict__ x,
                                                   const float* __restrict__ W,
                                                   unsigned short* __restrict__ xb,
                                                   int2* __restrict__ offs,
                                                   int* __restrict__ elist,
                                                   float* __restrict__ ri,
                                                   unsigned short* __restrict__ Whi,
                                                   unsigned short* __restrict__ Wlo,
                                                   int N, int NB) {
    __shared__ int h4[4][MAXRANGE];
    __shared__ int cw4[4][MAXRANGE];
    __shared__ float so_l[MAXRANGE];
    __shared__ int wsum[4];
    int tid = threadIdx.x, lane = tid & 63, w = tid >> 6, b = blockIdx.x;

    if (b < NB) {
        // ---- source bucket: deg_out hist (per-wave) -> so -> prescale ----
        #pragma unroll
        for (int i = 0; i < 4; ++i) h4[i][tid] = 0;
        __syncthreads();
        int cnt = curS[b];
        const unsigned* p32 = (const unsigned*)(srcB + (size_t)b * CAP);
        int nw = cnt >> 2;
        for (int i = tid; i < nw; i += 256) {
            unsigned v = p32[i];
            atomicAdd(&h4[w][v & 255], 1);
            atomicAdd(&h4[w][(v >> 8) & 255], 1);
            atomicAdd(&h4[w][(v >> 16) & 255], 1);
            atomicAdd(&h4[w][v >> 24], 1);
        }
        if (tid < (cnt & 3))
            atomicAdd(&h4[w][srcB[(size_t)b * CAP + nw * 4 + tid]], 1);
        __syncthreads();
        {
            int d = h4[0][tid] + h4[1][tid] + h4[2][tid] + h4[3][tid];
            if (d < 1) d = 1;
            so_l[tid] = rsqrtf((float)d);
        }
        __syncthreads();
        int row0 = b << BSHIFT;
        int nrows = N - row0; if (nrows > 256) nrows = 256;
        if (nrows <= 0) return;
        int nf4 = nrows * (N_FEAT / 4);
        const float4* xr = (const float4*)(x + (size_t)row0 * N_FEAT);
        ushort4* xo = (ushort4*)(xb + (size_t)row0 * N_FEAT);
        for (int i = tid; i < nf4; i += 256) {
            float s = so_l[i >> 5];
            float4 v = xr[i];
            xo[i] = make_ushort4(f2bf_rtne(s * v.x), f2bf_rtne(s * v.y),
                                 f2bf_rtne(s * v.z), f2bf_rtne(s * v.w));
        }
    } else if (b < 2 * NB) {
        // ---- target bucket: CSR build with 4-padding ----
        int bb = b - NB;
        #pragma unroll
        for (int i = 0; i < 4; ++i) h4[i][tid] = 0;
        __syncthreads();
        int cnt = curT[bb];
        int gbase = bb * CAP;
        for (int i = tid; i < cnt; i += 256)
            atomicAdd(&h4[w][(pairsT[(size_t)gbase + i] >> 16) & 255], 1);
        __syncthreads();
        int d0 = h4[0][tid], d1 = h4[1][tid], d2 = h4[2][tid], d3 = h4[3][tid];
        int deg = d0 + d1 + d2 + d3;
        int pdeg = (deg + 3) & ~3;                 // pad to multiple of 4
        int incl = wave_incl_scan(pdeg, lane);
        if (lane == 63) wsum[w] = incl;
        __syncthreads();
        int basew = 0;
        #pragma unroll
        for (int i = 0; i < 4; ++i) if (i < w) basew += wsum[i];
        int ex = basew + incl - pdeg;
        cw4[0][tid] = ex;
        cw4[1][tid] = ex + d0;
        cw4[2][tid] = ex + d0 + d1;
        cw4[3][tid] = ex + d0 + d1 + d2;
        int node = (bb << BSHIFT) + tid;
        if (node < N) {
            offs[node] = make_int2(gbase + ex, gbase + ex + pdeg);
            int dd = deg; if (dd < 1) dd = 1;
            ri[node] = rsqrtf((float)dd);
        }
        for (int p = deg; p < pdeg; ++p)           // pad slots -> zero row idx
            elist[gbase + ex + p] = N;
        __syncthreads();
        for (int i = tid; i < cnt; i += 256) {
            unsigned ww = pairsT[(size_t)gbase + i];
            int tl = (ww >> 16) & 255;
            int pos = atomicAdd(&cw4[w][tl], 1);   // cursor is bucket-absolute
            elist[gbase + pos] = (int)(ww & 0xFFFFu);
        }
    } else if (b < 2 * NB + 8) {
        // ---- W pack: B-fragment order, hi/lo split ----
        int idx = (b - 2 * NB) * 256 + tid;        // 0..2047
        int ln = idx & 63;
        int ks = (idx >> 6) & 3;
        int ct2 = idx >> 8;
        int n  = ct2 * 16 + (ln & 15);
        int k0 = ks * 32 + (ln >> 4) * 8;
        unsigned short h[8], l[8];
        #pragma unroll
        for (int j = 0; j < 8; ++j) {
            float wv = W[(k0 + j) * N_FEAT + n];
            unsigned short hh = f2bf_rtne(wv);
            h[j] = hh;
            l[j] = f2bf_rtne(wv - bf2f(hh));
        }
        size_t off = (size_t)idx * 8;
        *(ushort4*)(Whi + off)     = make_ushort4(h[0], h[1], h[2], h[3]);
        *(ushort4*)(Whi + off + 4) = make_ushort4(h[4], h[5], h[6], h[7]);
        *(ushort4*)(Wlo + off)     = make_ushort4(l[0], l[1], l[2], l[3]);
        *(ushort4*)(Wlo + off + 4) = make_ushort4(l[4], l[5], l[6], l[7]);
    } else {
        // ---- zero dummy row N of xb (gather target for pad edges) ----
        if (tid < 64) ((unsigned*)(xb + (size_t)N * N_FEAT))[tid] = 0;
    }
}

// Accumulate one gathered row (u32 = 2 bf16 feats) into a float2.
#define ACC_ROW(u, a) { a.x += __uint_as_float((u) << 16); \
                        a.y += __uint_as_float((u) & 0xffff0000u); }

// ---------------------------------------------------------------------------
// K3: FUSED agg + gemm. R11: the wave's 4 nodes are gathered CONCURRENTLY —
// per round, 4 aligned int4 scalar elist fetches (one per node; inactive
// nodes substitute the zero-row index N) + 16 independent row loads in
// flight (was 1 node's chain at a time). Degrees pre-padded to x4 by prep,
// so every batch is full and 16B-aligned: no tail loops.
// mfma layouts verified (R5/R7-R10 passed).
// ---------------------------------------------------------------------------
__global__ __launch_bounds__(256) void agg_gemm_kernel(const unsigned short* __restrict__ xb,
                                                       const int* __restrict__ elist,
                                                       const int2* __restrict__ offs,
                                                       const float* __restrict__ ri,
                                                       const unsigned short* __restrict__ Whi,
                                                       const unsigned short* __restrict__ Wlo,
                                                       const float* __restrict__ bias,
                                                       float* __restrict__ out,
                                                       int N) {
    __shared__ unsigned int hi_l[16 * LSTR];   // 4.2 KB
    __shared__ unsigned int lo_l[16 * LSTR];   // 4.2 KB
    int wave = threadIdx.x >> 6;
    int lane = threadIdx.x & 63;
    int quad = lane >> 4;
    int rowbase = blockIdx.x * 16;
    int col = lane * 2;

    // ---------------- phase 1: 4 nodes interleaved -> LDS ------------------
    int n0 = rowbase + wave * 4 + 0;
    int n1 = rowbase + wave * 4 + 1;
    int n2 = rowbase + wave * 4 + 2;
    int n3 = rowbase + wave * 4 + 3;
    int2 o0 = (n0 < N) ? offs[n0] : make_int2(0, 0);
    int2 o1 = (n1 < N) ? offs[n1] : make_int2(0, 0);
    int2 o2 = (n2 < N) ? offs[n2] : make_int2(0, 0);
    int2 o3 = (n3 < N) ? offs[n3] : make_int2(0, 0);
    int j0 = __builtin_amdgcn_readfirstlane(o0.x), e0v = __builtin_amdgcn_readfirstlane(o0.y);
    int j1 = __builtin_amdgcn_readfirstlane(o1.x), e1v = __builtin_amdgcn_readfirstlane(o1.y);
    int j2 = __builtin_amdgcn_readfirstlane(o2.x), e2v = __builtin_amdgcn_readfirstlane(o2.y);
    int j3 = __builtin_amdgcn_readfirstlane(o3.x), e3v = __builtin_amdgcn_readfirstlane(o3.y);
    float rr0 = (n0 < N) ? ri[n0] : 0.f;
    float rr1 = (n1 < N) ? ri[n1] : 0.f;
    float rr2 = (n2 < N) ? ri[n2] : 0.f;
    float rr3 = (n3 < N) ? ri[n3] : 0.f;
    float2 z = make_float2(0.f, 0.f);
    float2 A0[4] = {z, z, z, z}, A1[4] = {z, z, z, z};
    float2 A2[4] = {z, z, z, z}, A3[4] = {z, z, z, z};

    while (j0 < e0v || j1 < e1v || j2 < e2v || j3 < e3v) {
        int4 i0 = (j0 < e0v) ? *(const int4*)(elist + j0) : make_int4(N, N, N, N);
        int4 i1 = (j1 < e1v) ? *(const int4*)(elist + j1) : make_int4(N, N, N, N);
        int4 i2 = (j2 < e2v) ? *(const int4*)(elist + j2) : make_int4(N, N, N, N);
        int4 i3 = (j3 < e3v) ? *(const int4*)(elist + j3) : make_int4(N, N, N, N);
        unsigned u00 = *(const unsigned*)(xb + (size_t)i0.x * N_FEAT + col);
        unsigned u01 = *(const unsigned*)(xb + (size_t)i0.y * N_FEAT + col);
        unsigned u02 = *(const unsigned*)(xb + (size_t)i0.z * N_FEAT + col);
        unsigned u03 = *(const unsigned*)(xb + (size_t)i0.w * N_FEAT + col);
        unsigned u10 = *(const unsigned*)(xb + (size_t)i1.x * N_FEAT + col);
        unsigned u11 = *(const unsigned*)(xb + (size_t)i1.y * N_FEAT + col);
        unsigned u12 = *(const unsigned*)(xb + (size_t)i1.z * N_FEAT + col);
        unsigned u13 = *(const unsigned*)(xb + (size_t)i1.w * N_FEAT + col);
        unsigned u20 = *(const unsigned*)(xb + (size_t)i2.x * N_FEAT + col);
        unsigned u21 = *(const unsigned*)(xb + (size_t)i2.y * N_FEAT + col);
        unsigned u22 = *(const unsigned*)(xb + (size_t)i2.z * N_FEAT + col);
        unsigned u23 = *(const unsigned*)(xb + (size_t)i2.w * N_FEAT + col);
        unsigned u30 = *(const unsigned*)(xb + (size_t)i3.x * N_FEAT + col);
        unsigned u31 = *(const unsigned*)(xb + (size_t)i3.y * N_FEAT + col);
        unsigned u32r = *(const unsigned*)(xb + (size_t)i3.z * N_FEAT + col);
        unsigned u33 = *(const unsigned*)(xb + (size_t)i3.w * N_FEAT + col);
        ACC_ROW(u00, A0[0]) ACC_ROW(u01, A0[1]) ACC_ROW(u02, A0[2]) ACC_ROW(u03, A0[3])
        ACC_ROW(u10, A1[0]) ACC_ROW(u11, A1[1]) ACC_ROW(u12, A1[2]) ACC_ROW(u13, A1[3])
        ACC_ROW(u20, A2[0]) ACC_ROW(u21, A2[1]) ACC_ROW(u22, A2[2]) ACC_ROW(u23, A2[3])
        ACC_ROW(u30, A3[0]) ACC_ROW(u31, A3[1]) ACC_ROW(u32r, A3[2]) ACC_ROW(u33, A3[3])
        j0 += (j0 < e0v) ? 4 : 0;
        j1 += (j1 < e1v) ? 4 : 0;
        j2 += (j2 < e2v) ? 4 : 0;
        j3 += (j3 < e3v) ? 4 : 0;
    }

    int rbase = wave * 4;
    {
        float vx = ((A0[0].x + A0[1].x) + (A0[2].x + A0[3].x)) * rr0;
        float vy = ((A0[0].y + A0[1].y) + (A0[2].y + A0[3].y)) * rr0;
        unsigned short hx = f2bf_rtne(vx), hy = f2bf_rtne(vy);
        unsigned short lx = f2bf_rtne(vx - bf2f(hx)), ly = f2bf_rtne(vy - bf2f(hy));
        hi_l[(rbase + 0) * LSTR + lane] = (unsigned)hx | ((unsigned)hy << 16);
        lo_l[(rbase + 0) * LSTR + lane] = (unsigned)lx | ((unsigned)ly << 16);
    }
    {
        float vx = ((A1[0].x + A1[1].x) + (A1[2].x + A1[3].x)) * rr1;
        float vy = ((A1[0].y + A1[1].y) + (A1[2].y + A1[3].y)) * rr1;
        unsigned short hx = f2bf_rtne(vx), hy = f2bf_rtne(vy);
        unsigned short lx = f2bf_rtne(vx - bf2f(hx)), ly = f2bf_rtne(vy - bf2f(hy));
        hi_l[(rbase + 1) * LSTR + lane] = (unsigned)hx | ((unsigned)hy << 16);
        lo_l[(rbase + 1) * LSTR + lane] = (unsigned)lx | ((unsigned)ly << 16);
    }
    {
        float vx = ((A2[0].x + A2[1].x) + (A2[2].x + A2[3].x)) * rr2;
        float vy = ((A2[0].y + A2[1].y) + (A2[2].y + A2[3].y)) * rr2;
        unsigned short hx = f2bf_rtne(vx), hy = f2bf_rtne(vy);
        unsigned short lx = f2bf_rtne(vx - bf2f(hx)), ly = f2bf_rtne(vy - bf2f(hy));
        hi_l[(rbase + 2) * LSTR + lane] = (unsigned)hx | ((unsigned)hy << 16);
        lo_l[(rbase + 2) * LSTR + lane] = (unsigned)lx | ((unsigned)ly << 16);
    }
    {
        float vx = ((A3[0].x + A3[1].x) + (A3[2].x + A3[3].x)) * rr3;
        float vy = ((A3[0].y + A3[1].y) + (A3[2].y + A3[3].y)) * rr3;
        unsigned short hx = f2bf_rtne(vx), hy = f2bf_rtne(vy);
        unsigned short lx = f2bf_rtne(vx - bf2f(hx)), ly = f2bf_rtne(vy - bf2f(hy));
        hi_l[(rbase + 3) * LSTR + lane] = (unsigned)hx | ((unsigned)hy << 16);
        lo_l[(rbase + 3) * LSTR + lane] = (unsigned)lx | ((unsigned)ly << 16);
    }
    __syncthreads();

    // ---------------- phase 2: 16x128 MFMA tile (unchanged) ----------------
    bf16x8 Ahi[4], Alo[4];
    int m = lane & 15;
    #pragma unroll
    for (int ks = 0; ks < 4; ++ks) {
        int a = m * LSTR + ks * 16 + quad * 4;
        Ahi[ks] = *(const bf16x8*)(hi_l + a);
        Alo[ks] = *(const bf16x8*)(lo_l + a);
    }
    const bf16x8* BH = (const bf16x8*)Whi;
    const bf16x8* BL = (const bf16x8*)Wlo;

    #pragma unroll
    for (int c = 0; c < 2; ++c) {
        int ct = wave * 2 + c;
        f32x4 acc = {0.f, 0.f, 0.f, 0.f};
        #pragma unroll
        for (int ks = 0; ks < 4; ++ks) {
            bf16x8 bh = BH[(ct * 4 + ks) * 64 + lane];
            bf16x8 bl = BL[(ct * 4 + ks) * 64 + lane];
            acc = __builtin_amdgcn_mfma_f32_16x16x32_bf16(Ahi[ks], bh, acc, 0, 0, 0);
            acc = __builtin_amdgcn_mfma_f32_16x16x32_bf16(Alo[ks], bh, acc, 0, 0, 0);
            acc = __builtin_amdgcn_mfma_f32_16x16x32_bf16(Ahi[ks], bl, acc, 0, 0, 0);
        }
        int colc = ct * 16 + m;
        float bv = bias[colc];
        #pragma unroll
        for (int reg = 0; reg < 4; ++reg) {
            int r = rowbase + quad * 4 + reg;
            if (r < N)
                out[(size_t)r * N_FEAT + colc] = fmaxf(acc[reg] + bv, 0.f);
        }
    }
}

// ---------------------------------------------------------------------------
extern "C" void kernel_launch(void* const* d_in, const int* in_sizes, int n_in,
                              void* d_out, int out_size, void* d_ws, size_t ws_size,
                              hipStream_t stream) {
    const float* x      = (const float*)d_in[0];
    const int*   source = (const int*)d_in[1];
    const int*   target = (const int*)d_in[2];
    const float* W      = (const float*)d_in[3];
    const float* bias   = (const float*)d_in[4];
    float*       out    = (float*)d_out;

    const int N = in_sizes[0] / N_FEAT;   // 50000
    const int E = in_sizes[1];            // 800000

    const int NB   = (N + MAXRANGE - 1) >> BSHIFT;  // 196
    const int NBLK = (E + CHUNK - 1) / CHUNK;       // 782

    uintptr_t p = (uintptr_t)d_ws;
    auto carve = [&](size_t bytes) {
        p = (p + 255) & ~(uintptr_t)255;
        uintptr_t r = p;
        p += bytes;
        return (void*)r;
    };
    int*            curs    = (int*)carve((size_t)2 * NB * sizeof(int)); // curT|curS (memset)
    int*            curT    = curs;
    int*            curS    = curs + NB;
    unsigned int*   pairsT  = (unsigned int*)carve((size_t)NB * CAP * sizeof(unsigned int));
    int*            elist   = (int*)carve((size_t)NB * CAP * sizeof(int));
    unsigned char*  srcB    = (unsigned char*)carve((size_t)NB * CAP);
    float*          ri      = (float*)carve((size_t)N * sizeof(float));
    int2*           offs    = (int2*)carve((size_t)N * sizeof(int2));
    unsigned short* xb      = (unsigned short*)carve((size_t)(N + 1) * N_FEAT * sizeof(unsigned short)); // +1: zero row
    unsigned short* Whi     = (unsigned short*)carve((size_t)N_FEAT * N_FEAT * sizeof(unsigned short));
    unsigned short* Wlo     = (unsigned short*)carve((size_t)N_FEAT * N_FEAT * sizeof(unsigned short));
    (void)ws_size; (void)n_in; (void)out_size;

    (void)hipMemsetAsync(curs, 0, (size_t)2 * NB * sizeof(int), stream);

    scatter_kernel<<<NBLK, 256, 0, stream>>>(source, target, curT, curS, pairsT, srcB, E, NB);
    prep_kernel<<<2 * NB + 9, 256, 0, stream>>>(srcB, pairsT, curT, curS, x, W,
                                                xb, offs, elist, ri, Whi, Wlo, N, NB);
    agg_gemm_kernel<<<(N + 15) / 16, 256, 0, stream>>>(xb, elist, offs, ri,
                                                       Whi, Wlo, bias, out, N);
}